// Round 1
// baseline (274.632 us; speedup 1.0000x reference)
//
#include <hip/hip_runtime.h>
#include <math.h>

#define NCLS 1000
#define NB   32768
#define MAXP 128
#define MAXM 8

#define K1_BLOCKS 2048
#define K3_BLOCKS 4096

// ---- workspace layout (bytes) ----
#define OFF_CE    0u          // double[K1_BLOCKS]                 16384
#define OFF_PAUC  16384u      // double[K3_BLOCKS]                 32768
#define OFF_CNT   49152u      // int[1024]                          4096
#define OFF_ROW   53248u      // float4[NB]                       524288
#define OFF_POS   577536u     // float[NCLS*MAXP]                 512000
#define OFF_RTAB  1089536u    // float[NCLS*MAXM]                  32000
#define OFF_AUX   1121536u    // float2[NCLS]                       8000
#define OFF_REJ   1129536u    // float[NCLS]                        4000
// total ~1.08 MB

__device__ inline float wave_max_f(float v) {
#pragma unroll
    for (int m = 32; m >= 1; m >>= 1) v = fmaxf(v, __shfl_xor(v, m, 64));
    return v;
}
__device__ inline float wave_sum_f(float v) {
#pragma unroll
    for (int m = 32; m >= 1; m >>= 1) v += __shfl_xor(v, m, 64);
    return v;
}
__device__ inline double wave_sum_d(double v) {
#pragma unroll
    for (int m = 32; m >= 1; m >>= 1) {
        long long b = __double_as_longlong(v);
        b = __shfl_xor(b, m, 64);
        v += __longlong_as_double(b);
    }
    return v;
}

// zero the per-class counters (ws is poisoned 0xAA before every timed call)
__global__ void pauc_init(int* __restrict__ cnt) {
    if (threadIdx.x < 1024) cnt[threadIdx.x] = 0;
}

// Kernel 1: one wave per row. Computes M, S, L = M + log S; CE partial;
// scatters positive-class prob into per-class bucket.
__global__ __launch_bounds__(256)
void pauc_k1_rows(const float* __restrict__ pred, const int* __restrict__ tgt,
                  const float* __restrict__ w, float4* __restrict__ rowdata,
                  float* __restrict__ posScores, int* __restrict__ cnt,
                  double* __restrict__ ce_part) {
    const int lane = threadIdx.x & 63;
    const int wid  = threadIdx.x >> 6;
    const int gw   = blockIdx.x * 4 + wid;          // 0..8191

    // weight chunks are row-invariant: hoist
    float4 wv[4];
    float sw_p = 0.f;
#pragma unroll
    for (int i = 0; i < 4; ++i) {
        int f = i * 64 + lane;
        if (f < 250) {
            wv[i] = reinterpret_cast<const float4*>(w)[f];
            sw_p += wv[i].x + wv[i].y + wv[i].z + wv[i].w;
        } else {
            wv[i] = make_float4(0.f, 0.f, 0.f, 0.f);
        }
    }
    const float SW = wave_sum_f(sw_p);

    double ce_acc = 0.0;
    for (int row = gw; row < NB; row += 8192) {
        const float4* rp4 = reinterpret_cast<const float4*>(pred + (size_t)row * NCLS);
        float4 v[4];
        float vmax = -3.0e38f;
#pragma unroll
        for (int i = 0; i < 4; ++i) {
            int f = i * 64 + lane;
            if (f < 250) {
                v[i] = rp4[f];
                vmax = fmaxf(vmax, fmaxf(fmaxf(v[i].x, v[i].y), fmaxf(v[i].z, v[i].w)));
            } else {
                v[i] = make_float4(0.f, 0.f, 0.f, 0.f);
            }
        }
        const float M = wave_max_f(vmax);

        float s_p = 0.f, wx_p = 0.f;
#pragma unroll
        for (int i = 0; i < 4; ++i) {
            int f = i * 64 + lane;
            if (f < 250) {
                s_p  += __expf(v[i].x - M) + __expf(v[i].y - M)
                      + __expf(v[i].z - M) + __expf(v[i].w - M);
                wx_p += wv[i].x * v[i].x + wv[i].y * v[i].y
                      + wv[i].z * v[i].z + wv[i].w * v[i].w;
            }
        }
        const float S  = wave_sum_f(s_p);
        const float WX = wave_sum_f(wx_p);

        if (lane == 0) {
            const float invS = 1.0f / S;
            const float L    = M + logf(S);
            const int   y    = tgt[row];
            const float xy   = pred[(size_t)row * NCLS + y];
            const float wy   = w[y];
            // sum_c t_c*w_c*logp_c = 0.9*w_y*(x_y-L) + 1e-4*(WX - SW*L)
            ce_acc += (double)(0.9f * wy * (xy - L) + 1e-4f * (WX - SW * L));
            rowdata[row] = make_float4(M, invS, L, 0.f);
            const int p = atomicAdd(&cnt[y], 1);
            if (p < MAXP) posScores[y * MAXP + p] = __expf(xy - M) * invS;
        }
    }

    __shared__ double sred[4];
    if (lane == 0) sred[wid] = ce_acc;
    __syncthreads();
    if (threadIdx.x == 0)
        ce_part[blockIdx.x] = sred[0] + sred[1] + sred[2] + sred[3];
}

// Kernel 2: per class, rank the P positive scores, keep bottom m = P-k0+1
// (descending: r[0]=q_k0 ... r[m-1]=q_P), emit reject threshold + coef.
__global__ __launch_bounds__(128)
void pauc_k2_thresh(const float* __restrict__ posScores, const int* __restrict__ cnt,
                    const float* __restrict__ w, float* __restrict__ rtab,
                    float2* __restrict__ aux, float* __restrict__ rej) {
    const int c = blockIdx.x;
    const int t = threadIdx.x;
    __shared__ float vals[MAXP];
    __shared__ float rloc[MAXM];
    __shared__ int   k0s;

    int P = cnt[c];
    if (P > MAXP) P = MAXP;   // statistically impossible at B/C ~ 33
    if (t < MAXM) rloc[t] = -1.0f;
    if (t < P) vals[t] = posScores[c * MAXP + t];
    if (t == 0) {
        int k0 = 1;
        if (P > 0) {
            for (int k = 1; k <= P; ++k) {
                if ((float)k / (float)P >= 0.95f) { k0 = k; break; }  // exact fp32 semantics
            }
        }
        k0s = k0;
    }
    __syncthreads();

    if (P == 0) {   // reference: mask never true -> pauc = 0
        if (t == 0) { rej[c] = -3.0e38f; aux[c] = make_float2(0.f, 0.f); }
        if (t < MAXM) rtab[c * MAXM + t] = -1.0f;
        return;
    }
    const int k0 = k0s;

    if (t < P) {
        const float v = vals[t];
        int rank = 0;   // descending rank, ties broken by index (any consistent order works)
        for (int u = 0; u < P; ++u) {
            const float vu = vals[u];
            rank += (vu > v) ? 1 : ((vu == v && u < t) ? 1 : 0);
        }
        const int idx = rank - (k0 - 1);
        if (idx >= 0 && idx < MAXM) rloc[idx] = v;   // m <= 7 for P <= 128
    }
    __syncthreads();

    if (t < MAXM) rtab[c * MAXM + t] = rloc[t];
    if (t == 0) {
        const float r1 = rloc[0];                    // q_{k0}
        rej[c] = logf(r1) + 1e-3f;                   // conservative log-space reject
        aux[c] = make_float2((float)(k0 - 1),
                             w[c] / ((float)P * (float)(NB - P)));
    }
}

// Kernel 3: stream the matrix; fast log-space reject, exact prob-space tail.
__global__ __launch_bounds__(256)
void pauc_k3_scan(const float* __restrict__ pred, const int* __restrict__ tgt,
                  const float4* __restrict__ rowdata, const float* __restrict__ rej,
                  const float* __restrict__ rtab, const float2* __restrict__ aux,
                  double* __restrict__ pauc_part) {
    const int t = threadIdx.x;
    double acc = 0.0;

    float4 rj = make_float4(-3.0e38f, -3.0e38f, -3.0e38f, -3.0e38f);
    if (t < 250) rj = reinterpret_cast<const float4*>(rej)[t];   // row-invariant: hoist

    for (int row = blockIdx.x; row < NB; row += K3_BLOCKS) {
        const float4 rd = rowdata[row];      // broadcast
        const int    y  = tgt[row];
        if (t < 250) {
            const float4 x = reinterpret_cast<const float4*>(pred + (size_t)row * NCLS)[t];
            const float M = rd.x, invS = rd.y, L = rd.z;
            const float xv[4] = {x.x, x.y, x.z, x.w};
            const float rs[4] = {rj.x, rj.y, rj.z, rj.w};
#pragma unroll
            for (int e = 0; e < 4; ++e) {
                const int c = 4 * t + e;
                if (xv[e] - L < rs[e] && c != y) {
                    const float s = __expf(xv[e] - M) * invS;   // same formula as k1 positives
                    const float* rt = rtab + c * MAXM;
                    if (s < rt[0]) {      // strictly below q_{k0} -> always masked
                        int gt = 0, eq = 0;
#pragma unroll
                        for (int i = 0; i < MAXM; ++i) {
                            const float r = rt[i];
                            gt += (r > s) ? 1 : 0;
                            eq += (r == s) ? 1 : 0;
                        }
                        const float2 a = aux[c];
                        // (a_j + 0.5 e_j) * w_c / (P*N)
                        acc += (double)((a.x + (float)gt + 0.5f * (float)eq) * a.y);
                    }
                }
            }
        }
    }

    acc = wave_sum_d(acc);
    __shared__ double sred[4];
    if ((threadIdx.x & 63) == 0) sred[threadIdx.x >> 6] = acc;
    __syncthreads();
    if (threadIdx.x == 0)
        pauc_part[blockIdx.x] = sred[0] + sred[1] + sred[2] + sred[3];
}

// Kernel 4: deterministic finalize.
__global__ __launch_bounds__(256)
void pauc_k4_final(const double* __restrict__ ce_part, const double* __restrict__ pauc_part,
                   const float* __restrict__ w, float* __restrict__ out) {
    const int t = threadIdx.x;
    double ce = 0.0, pa = 0.0, sw = 0.0;
    for (int i = t; i < K1_BLOCKS; i += 256) ce += ce_part[i];
    for (int i = t; i < K3_BLOCKS; i += 256) pa += pauc_part[i];
    for (int i = t; i < NCLS;      i += 256) sw += (double)w[i];
    ce = wave_sum_d(ce); pa = wave_sum_d(pa); sw = wave_sum_d(sw);
    __shared__ double sc[4], sp[4], ss[4];
    const int lane = t & 63, wid = t >> 6;
    if (lane == 0) { sc[wid] = ce; sp[wid] = pa; ss[wid] = sw; }
    __syncthreads();
    if (t == 0) {
        const double ceS = sc[0] + sc[1] + sc[2] + sc[3];
        const double paS = sp[0] + sp[1] + sp[2] + sp[3];
        const double swS = ss[0] + ss[1] + ss[2] + ss[3];
        const double ce_loss = -ceS / (double)NB;
        const double avg     = paS / (swS * (1.0 - 0.95));     // max_pauc
        out[0] = (float)(ce_loss - log(avg + 1e-7));
    }
}

extern "C" void kernel_launch(void* const* d_in, const int* in_sizes, int n_in,
                              void* d_out, int out_size, void* d_ws, size_t ws_size,
                              hipStream_t stream) {
    const float* pred = (const float*)d_in[0];
    const int*   tgt  = (const int*)d_in[1];     // jax default: int32
    const float* w    = (const float*)d_in[2];

    char* ws = (char*)d_ws;
    double* ce_part   = (double*)(ws + OFF_CE);
    double* pauc_part = (double*)(ws + OFF_PAUC);
    int*    cnt       = (int*)   (ws + OFF_CNT);
    float4* rowdata   = (float4*)(ws + OFF_ROW);
    float*  posScores = (float*) (ws + OFF_POS);
    float*  rtab      = (float*) (ws + OFF_RTAB);
    float2* aux       = (float2*)(ws + OFF_AUX);
    float*  rej       = (float*) (ws + OFF_REJ);

    pauc_init<<<1, 1024, 0, stream>>>(cnt);
    pauc_k1_rows<<<K1_BLOCKS, 256, 0, stream>>>(pred, tgt, w, rowdata, posScores, cnt, ce_part);
    pauc_k2_thresh<<<NCLS, 128, 0, stream>>>(posScores, cnt, w, rtab, aux, rej);
    pauc_k3_scan<<<K3_BLOCKS, 256, 0, stream>>>(pred, tgt, rowdata, rej, rtab, aux, pauc_part);
    pauc_k4_final<<<1, 256, 0, stream>>>(ce_part, pauc_part, w, (float*)d_out);
}